// Round 7
// baseline (257.504 us; speedup 1.0000x reference)
//
#include <hip/hip_runtime.h>

typedef __attribute__((ext_vector_type(8))) __bf16 bf16x8;
typedef __attribute__((ext_vector_type(4))) float  f32x4;

#define DEV __device__ __forceinline__

DEV void async_copy16(const void* g, void* l) {
  __builtin_amdgcn_global_load_lds((const __attribute__((address_space(1))) void*)g,
                                   (__attribute__((address_space(3))) void*)l, 16, 0, 0);
}

// load element i of a raw input as float; isbf chooses bf16 vs fp32 interpretation
DEV float ldf(const void* p, size_t i, int isbf) {
  if (isbf) {
    unsigned int w = ((unsigned int)((const unsigned short*)p)[i]) << 16;
    float f; __builtin_memcpy(&f, &w, 4); return f;
  }
  return ((const float*)p)[i];
}

// uniform per-block dtype probe on x's first 64 halfwords (scalar loads; all lanes agree)
DEV int detect_isbf(const unsigned short* __restrict__ x) {
  int bad = 0;
#pragma unroll
  for (int i = 0; i < 64; i++) {
    int e = (x[i] >> 7) & 0xFF;
    bad |= (e >= 0x90) ? 1 : 0;
  }
  return !bad;
}

// ---- fused prep: z<4 -> transpose weight z into bf16 [C][R]; z==4 -> x cast (fp32 only) + bias ----
__global__ __launch_bounds__(256) void prep(const void* __restrict__ Wq,
                                            const void* __restrict__ Wk,
                                            const void* __restrict__ Wv,
                                            const void* __restrict__ Wo,
                                            const void* __restrict__ x,
                                            const void* __restrict__ bq,
                                            const void* __restrict__ bk,
                                            const void* __restrict__ bv,
                                            const void* __restrict__ bo,
                                            __bf16* __restrict__ Wt,
                                            __bf16* __restrict__ Wot,
                                            __bf16* __restrict__ x_bf,
                                            float* __restrict__ bias) {
  __shared__ float tile[32][33];
  const int isbf = detect_isbf((const unsigned short*)x);
  const int tid = threadIdx.x;
  const int z = blockIdx.z;

  if (z < 4) {
    const void* in = (z == 0) ? Wq : (z == 1) ? Wk : (z == 2) ? Wv : Wo;
    __bf16* out = (z < 3) ? (Wt + (size_t)z * 1024 * 1024) : Wot;
    const int tx = tid & 31, ty = tid >> 5;
    const int r0 = blockIdx.y * 32, c0 = blockIdx.x * 32;
#pragma unroll
    for (int i = 0; i < 4; i++) {
      int r = ty + i * 8;
      tile[r][tx] = ldf(in, (size_t)(r0 + r) * 1024 + c0 + tx, isbf);
    }
    __syncthreads();
#pragma unroll
    for (int i = 0; i < 4; i++) {
      int r = ty + i * 8;
      out[(size_t)(c0 + r) * 1024 + r0 + tx] = (__bf16)tile[tx][r];
    }
  } else {
    const int id = blockIdx.y * 32 + blockIdx.x;  // 0..1023
    if (!isbf) {
#pragma unroll
      for (int j = 0; j < 4; j++) {
        int idx = id * 1024 + j * 256 + tid;
        float4 f = ((const float4*)x)[idx];
        union { __bf16 h[4]; uint2 u; } pk;
        pk.h[0] = (__bf16)f.x; pk.h[1] = (__bf16)f.y;
        pk.h[2] = (__bf16)f.z; pk.h[3] = (__bf16)f.w;
        ((uint2*)x_bf)[idx] = pk.u;
      }
    }
    if (id < 16) {
      int i = id * 256 + tid;
      if (i < 1024)      bias[i] = ldf(bq, i, isbf);
      else if (i < 2048) bias[i] = ldf(bk, i - 1024, isbf);
      else if (i < 3072) bias[i] = ldf(bv, i - 2048, isbf);
      else               bias[i] = ldf(bo, i - 3072, isbf);
    }
  }
}

// ---------------- GEMM: C[M,NT-tiled] = A[M,K] @ Bt[N,K]^T + bias ----------------
template <int DYN, int NT, int ALT>
__global__ __launch_bounds__(256, 2) void gemm_bt(const __bf16* __restrict__ A,
                                                  const __bf16* __restrict__ Aalt,
                                                  const __bf16* __restrict__ Bt,
                                                  const float* __restrict__ bias,
                                                  void* __restrict__ Cout,
                                                  const unsigned short* __restrict__ xdet,
                                                  int M, int N, int K) {
  constexpr int WN = NT / 2;
  constexpr int JB = WN / 16;
  constexpr int NR = NT / 32;
  __shared__ __align__(16) __bf16 As[128 * 64];
  __shared__ __align__(16) __bf16 Bs[NT * 64];
  const int tid = threadIdx.x;
  const int wid = tid >> 6, lane = tid & 63;
  const int m_blk = blockIdx.x * 128, n_blk = blockIdx.y * NT;
  const int wm = (wid & 1) * 64, wn = (wid >> 1) * WN;
  const int l8 = lane >> 3, l7 = lane & 7;
  const int cc = l7 ^ (l8 & 7);
  const int q4 = lane >> 4, l15 = lane & 15;

  int isbf = 1;
  if (DYN || ALT) isbf = detect_isbf(xdet);
  const __bf16* Ap = (ALT && isbf) ? Aalt : A;

  f32x4 acc[4][JB] = {};

  for (int kb = 0; kb < K; kb += 64) {
    __syncthreads();
#pragma unroll
    for (int i = 0; i < 4; i++) {
      int row = i * 32 + wid * 8 + l8;
      async_copy16(Ap + (size_t)(m_blk + row) * K + kb + cc * 8,
                   As + (i * 32 + wid * 8) * 64);
    }
#pragma unroll
    for (int i = 0; i < NR; i++) {
      int row = i * 32 + wid * 8 + l8;
      async_copy16(Bt + (size_t)(n_blk + row) * K + kb + cc * 8,
                   Bs + (i * 32 + wid * 8) * 64);
    }
    __syncthreads();
#pragma unroll
    for (int k0 = 0; k0 < 64; k0 += 32) {
      bf16x8 a[4], b[JB];
#pragma unroll
      for (int i = 0; i < 4; i++) {
        int ra = wm + i * 16 + l15;
        int ba = ra * 8 + (((k0 >> 3) + q4) ^ (ra & 7));
        a[i] = *(const bf16x8*)&As[ba * 8];
      }
#pragma unroll
      for (int j = 0; j < JB; j++) {
        int rb = wn + j * 16 + l15;
        int bb = rb * 8 + (((k0 >> 3) + q4) ^ (rb & 7));
        b[j] = *(const bf16x8*)&Bs[bb * 8];
      }
#pragma unroll
      for (int i = 0; i < 4; i++)
#pragma unroll
        for (int j = 0; j < JB; j++)
          acc[i][j] = __builtin_amdgcn_mfma_f32_16x16x32_bf16(a[i], b[j], acc[i][j], 0, 0, 0);
    }
  }

  float bcol[JB];
#pragma unroll
  for (int j = 0; j < JB; j++) bcol[j] = bias[n_blk + wn + j * 16 + l15];
#pragma unroll
  for (int i = 0; i < 4; i++)
#pragma unroll
    for (int j = 0; j < JB; j++) {
      int col = n_blk + wn + j * 16 + l15;
#pragma unroll
      for (int r = 0; r < 4; r++) {
        int row = m_blk + wm + i * 16 + q4 * 4 + r;
        float v = acc[i][j][r] + bcol[j];
        size_t idx = (size_t)row * N + col;
        if (DYN && !isbf) ((float*)Cout)[idx] = v;
        else              ((__bf16*)Cout)[idx] = (__bf16)v;
      }
    }
}

// ---------------- LN + RoPE + V-transpose (fused) ----------------
__global__ __launch_bounds__(256) void ln_rope_v(const __bf16* __restrict__ qkv,
                                                 const void* __restrict__ rcos,
                                                 const void* __restrict__ rsin,
                                                 const void* __restrict__ qw,
                                                 const void* __restrict__ qb,
                                                 const void* __restrict__ kw,
                                                 const void* __restrict__ kb_,
                                                 const unsigned short* __restrict__ xdet,
                                                 __bf16* __restrict__ Qp,
                                                 __bf16* __restrict__ Kp,
                                                 __bf16* __restrict__ Vt) {
  __shared__ __bf16 vt[64][68];
  const int isbf = detect_isbf(xdet);
  const int tid = threadIdx.x, w = tid >> 6, lane = tid & 63;
  const int bh = blockIdx.y, h = bh & 15, b = bh >> 4;
  const int n0 = blockIdx.x * 64;

  float gq = ldf(qw, lane, isbf), bq_ = ldf(qb, lane, isbf);
  float gk = ldf(kw, lane, isbf), bk_ = ldf(kb_, lane, isbf);

  for (int t = 0; t < 16; t++) {
    const int n = n0 + w * 16 + t;
    const size_t tok = (size_t)b * 2048 + n;
    const __bf16* base = qkv + tok * 3072 + h * 192;
    float qv = (float)base[lane], kv = (float)base[64 + lane], vv = (float)base[128 + lane];

    float sq = qv, sk = kv;
#pragma unroll
    for (int m = 1; m < 64; m <<= 1) { sq += __shfl_xor(sq, m, 64); sk += __shfl_xor(sk, m, 64); }
    float muq = sq * (1.0f / 64.0f), muk = sk * (1.0f / 64.0f);
    float tq = qv - muq, tk = kv - muk;
    float vq = tq * tq, vk = tk * tk;
#pragma unroll
    for (int m = 1; m < 64; m <<= 1) { vq += __shfl_xor(vq, m, 64); vk += __shfl_xor(vk, m, 64); }
    float rsq = rsqrtf(vq * (1.0f / 64.0f) + 1e-6f);
    float rsk = rsqrtf(vk * (1.0f / 64.0f) + 1e-6f);
    float qn = tq * rsq * gq + bq_;
    float kn = tk * rsk * gk + bk_;

    float c = ldf(rcos, tok * 64 + lane, isbf), s = ldf(rsin, tok * 64 + lane, isbf);
    float qpart = __shfl_xor(qn, 32, 64), kpart = __shfl_xor(kn, 32, 64);
    float qrh = (lane < 32) ? -qpart : qpart;
    float krh = (lane < 32) ? -kpart : kpart;

    const size_t oidx = ((size_t)bh * 2048 + n) * 64 + lane;
    Qp[oidx] = (__bf16)((qn * c + qrh * s) * 0.1803368801111204f);  // 0.125 * log2(e)
    Kp[oidx] = (__bf16)(kn * c + krh * s);
    vt[lane][w * 16 + t] = (__bf16)vv;
  }
  __syncthreads();
  const int row = tid >> 2, qt = tid & 3;
  size_t gbase = (size_t)bh * 64 * 2048 + (size_t)row * 2048 + n0 + qt * 16;
#pragma unroll
  for (int u = 0; u < 4; u++)
    *(uint2*)&Vt[gbase + u * 4] = *(const uint2*)&vt[row][qt * 16 + u * 4];
}

// ---------------- flash attention: K-split x2, KT=32, 2-buffer, 24 KB LDS ----------------
// grid (16 qblk, 32 bh, 2 split) = 1024 blocks -> 4 blocks/CU = 16 waves/CU.
// No-max softmax partials are additive: each split writes fp32 partial O and l;
// combine() sums and normalizes. Per-wave: 32 q rows; per iter 32 keys:
// 8 MFMA QK (S^T = K.Q^T) + 16 exp2 + P round-trip in B-frag order + 8 MFMA PV.
__global__ __launch_bounds__(256, 4) void attn(const __bf16* __restrict__ Qp,
                                               const __bf16* __restrict__ Kp,
                                               const __bf16* __restrict__ Vt,
                                               float* __restrict__ O0,
                                               float* __restrict__ O1,
                                               float* __restrict__ lpart) {
  __shared__ __align__(16) __bf16 sK[2][2048];   // [buf][(g=ks*2+c)*64+lane]*8
  __shared__ __align__(16) __bf16 sV[2][2048];   // [buf][(ds*64+lane)]*8
  __shared__ __align__(16) __bf16 sP[4][1024];   // per-wave, B-frag order (32q x 32k)

  const int tid = threadIdx.x, wid = tid >> 6, lane = tid & 63;
  const int q4 = lane >> 4, l15 = lane & 15;
  const int bh = blockIdx.y, split = blockIdx.z;
  const int q0w = blockIdx.x * 128 + wid * 32;
  const int kt0 = split * 1024;
  const __bf16* Qb = Qp + (size_t)bh * 2048 * 64;
  const __bf16* Kb = Kp + (size_t)bh * 2048 * 64;
  const __bf16* Vb = Vt + (size_t)bh * 64 * 2048;
  float* Op = split ? O1 : O0;
  __bf16* sPw = &sP[wid][0];
  const int pbase = (q4 >> 1) * 128 + l15 * 8 + (q4 & 1) * 4;

  // Q fragments (B-operand): B[q=l15][k=q4*8+j], 2 chains of 32 d
  bf16x8 qf[2][2];
#pragma unroll
  for (int qs = 0; qs < 2; qs++)
#pragma unroll
    for (int c = 0; c < 2; c++)
      qf[qs][c] = *(const bf16x8*)&Qb[(size_t)(q0w + qs * 16 + l15) * 64 + c * 32 + q4 * 8];

  f32x4 o[2][4] = {};
  float lsum[2] = {0.f, 0.f};

  // per wave: 1 copy K (group wid: key=(wid>>1)*16+l15, d=(wid&1)*32+q4*8),
  //           1 copy V (group wid: d=wid*16+l15, k=q4*8)
#define STAGE(kt, bf)                                                                    \
  do {                                                                                   \
    async_copy16(Kb + (size_t)((kt) + (wid >> 1) * 16 + l15) * 64 + (wid & 1) * 32 + q4 * 8, \
                 &sK[bf][wid * 512]);                                                    \
    async_copy16(Vb + (size_t)(wid * 16 + l15) * 2048 + (kt) + q4 * 8,                   \
                 &sV[bf][wid * 512]);                                                    \
  } while (0)

  STAGE(kt0, 0);

  for (int it = 0; it < 32; ++it) {
    const int buf = it & 1;
    __syncthreads();  // readers of buf^1 done + loads into buf landed
    if (it < 31) STAGE(kt0 + (it + 1) * 32, buf ^ 1);

    // ---- QK^T (S^T): A = K rows (2 ks-subs), B = Q (2 q-subs), 2 d-chains ----
    bf16x8 ak[2][2];
#pragma unroll
    for (int ks = 0; ks < 2; ks++)
#pragma unroll
      for (int c = 0; c < 2; c++)
        ak[ks][c] = *(const bf16x8*)&sK[buf][((ks * 2 + c) * 64 + lane) * 8];
    f32x4 sc[2][2];
#pragma unroll
    for (int qs = 0; qs < 2; qs++)
#pragma unroll
      for (int ks = 0; ks < 2; ks++) {
        f32x4 z = {0.f, 0.f, 0.f, 0.f};
        z = __builtin_amdgcn_mfma_f32_16x16x32_bf16(ak[ks][0], qf[qs][0], z, 0, 0, 0);
        z = __builtin_amdgcn_mfma_f32_16x16x32_bf16(ak[ks][1], qf[qs][1], z, 0, 0, 0);
        sc[qs][ks] = z;
      }

    // ---- no-max softmax: p = exp2(s); store P in B-frag order ----
#pragma unroll
    for (int qs = 0; qs < 2; qs++)
#pragma unroll
      for (int ks = 0; ks < 2; ks++) {
        union { __bf16 h[4]; uint2 u; } pk;
#pragma unroll
        for (int r = 0; r < 4; r++) {
          float p = exp2f(sc[qs][ks][r]);
          lsum[qs] += p;
          pk.h[r] = (__bf16)p;
        }
        *(uint2*)&sPw[qs * 512 + ks * 256 + pbase] = pk.u;
      }
    asm volatile("s_waitcnt lgkmcnt(0)" ::: "memory");  // P writes -> reads (same wave)

    // ---- PV (O^T += V^T.P): single K=32 MFMA per (qs,ds) ----
    bf16x8 pb[2];
#pragma unroll
    for (int qs = 0; qs < 2; qs++)
      pb[qs] = *(const bf16x8*)&sPw[(qs * 64 + lane) * 8];
#pragma unroll
    for (int ds = 0; ds < 4; ds++) {
      bf16x8 av = *(const bf16x8*)&sV[buf][(ds * 64 + lane) * 8];
#pragma unroll
      for (int qs = 0; qs < 2; qs++)
        o[qs][ds] = __builtin_amdgcn_mfma_f32_16x16x32_bf16(av, pb[qs], o[qs][ds], 0, 0, 0);
    }
  }
#undef STAGE

  // ---- epilogue: partial O (fp32, [bh][q][d]) and partial l ----
#pragma unroll
  for (int qs = 0; qs < 2; qs++) {
    const int q = q0w + qs * 16 + l15;
    float l = lsum[qs];
    l += __shfl_xor(l, 16, 64);
    l += __shfl_xor(l, 32, 64);
    if (q4 == 0) lpart[(size_t)(split * 32 + bh) * 2048 + q] = l;
    size_t base = ((size_t)bh * 2048 + q) * 64;
#pragma unroll
    for (int ds = 0; ds < 4; ds++)
      *(f32x4*)&Op[base + ds * 16 + q4 * 4] = o[qs][ds];
  }
}

// ---------------- combine: Obuf = (O0+O1) / (l0+l1), bf16 [b][q][h*64+d] ----------------
__global__ __launch_bounds__(256) void combine(const float* __restrict__ O0,
                                               const float* __restrict__ O1,
                                               const float* __restrict__ lpart,
                                               __bf16* __restrict__ Obuf) {
  const int idx = blockIdx.x * 256 + threadIdx.x;  // 1,048,576 threads x 4 d
  const int d4 = idx & 15, q = (idx >> 4) & 2047, bh = idx >> 15;
  const int b = bh >> 4, h = bh & 15;
  const size_t po = ((size_t)bh * 2048 + q) * 64 + d4 * 4;
  f32x4 a = *(const f32x4*)&O0[po];
  f32x4 c = *(const f32x4*)&O1[po];
  float l = lpart[(size_t)bh * 2048 + q] + lpart[(size_t)(32 + bh) * 2048 + q];
  float rl = 1.0f / l;
  union { __bf16 h4[4]; uint2 u; } pk;
#pragma unroll
  for (int r = 0; r < 4; r++) pk.h4[r] = (__bf16)((a[r] + c[r]) * rl);
  *(uint2*)&Obuf[((size_t)(b * 2048 + q)) * 1024 + h * 64 + d4 * 4] = pk.u;
}

extern "C" void kernel_launch(void* const* d_in, const int* in_sizes, int n_in,
                              void* d_out, int out_size, void* d_ws, size_t ws_size,
                              hipStream_t stream) {
  const void* x   = d_in[0];
  const void* rc  = d_in[1];
  const void* rs  = d_in[2];
  const void* Wq  = d_in[3];
  const void* bq  = d_in[4];
  const void* Wk  = d_in[5];
  const void* bk  = d_in[6];
  const void* Wv  = d_in[7];
  const void* bv  = d_in[8];
  const void* qnw = d_in[9];
  const void* qnb = d_in[10];
  const void* knw = d_in[11];
  const void* knb = d_in[12];
  const void* Wo  = d_in[13];
  const void* bo  = d_in[14];
  const unsigned short* xdet = (const unsigned short*)x;

  // temporal aliasing plan:
  //  [0, 25165824)        qkv bf16 [4096][3072] (gemm0 -> ln_rope_v), then
  //  [0, 33554432)        O0/O1 fp32 partials (attn -> combine)
  //  [25165824, 33554432) x_bf (prep -> gemm0, fp32 path only; dead before attn)
  //  [33554432, 41943040) Qp, then Obuf (combine -> gemm1; Qp dead after attn)
  char* ws = (char*)d_ws;
  __bf16* qkv  = (__bf16*)ws;
  float*  O0   = (float*)ws;
  float*  O1   = (float*)(ws + 16777216);
  __bf16* x_bf = (__bf16*)(ws + 25165824);
  __bf16* Qp   = (__bf16*)(ws + 33554432);
  __bf16* Obuf = (__bf16*)(ws + 33554432);
  __bf16* Kp   = (__bf16*)(ws + 41943040);
  __bf16* Vt   = (__bf16*)(ws + 50331648);
  __bf16* Wt   = (__bf16*)(ws + 58720256);   // [3072][1024] 6 MB
  __bf16* Wot  = (__bf16*)(ws + 65011712);   // [1024][1024] 2 MB
  float*  bias = (float*)(ws + 67108864);    // [4096]
  float*  lprt = (float*)(ws + 67125248);    // [2][32][2048] 512 KB

  prep<<<dim3(32, 32, 5), 256, 0, stream>>>(Wq, Wk, Wv, Wo, x, bq, bk, bv, bo,
                                            Wt, Wot, x_bf, bias);
  gemm_bt<0, 128, 1><<<dim3(32, 24), 256, 0, stream>>>(x_bf, (const __bf16*)x, Wt, bias,
                                                       qkv, xdet, 4096, 3072, 1024);
  ln_rope_v<<<dim3(32, 32), 256, 0, stream>>>(qkv, rc, rs, qnw, qnb, knw, knb, xdet,
                                              Qp, Kp, Vt);
  attn<<<dim3(16, 32, 2), 256, 0, stream>>>(Qp, Kp, Vt, O0, O1, lprt);
  combine<<<4096, 256, 0, stream>>>(O0, O1, lprt, Obuf);
  gemm_bt<1, 64, 0><<<dim3(32, 16), 256, 0, stream>>>(Obuf, nullptr, Wot, bias + 3072,
                                                      d_out, xdet, 4096, 1024, 1024);
}

// Round 8
// 242.111 us; speedup vs baseline: 1.0636x; 1.0636x over previous
//
#include <hip/hip_runtime.h>

typedef __attribute__((ext_vector_type(8))) __bf16 bf16x8;
typedef __attribute__((ext_vector_type(4))) float  f32x4;

#define DEV __device__ __forceinline__

DEV void async_copy16(const void* g, void* l) {
  __builtin_amdgcn_global_load_lds((const __attribute__((address_space(1))) void*)g,
                                   (__attribute__((address_space(3))) void*)l, 16, 0, 0);
}

// load element i of a raw input as float; isbf chooses bf16 vs fp32 interpretation
DEV float ldf(const void* p, size_t i, int isbf) {
  if (isbf) {
    unsigned int w = ((unsigned int)((const unsigned short*)p)[i]) << 16;
    float f; __builtin_memcpy(&f, &w, 4); return f;
  }
  return ((const float*)p)[i];
}

// uniform per-block dtype probe on x's first 64 halfwords (scalar loads; all lanes agree)
DEV int detect_isbf(const unsigned short* __restrict__ x) {
  int bad = 0;
#pragma unroll
  for (int i = 0; i < 64; i++) {
    int e = (x[i] >> 7) & 0xFF;
    bad |= (e >= 0x90) ? 1 : 0;
  }
  return !bad;
}

// ---- fused prep: z<4 -> transpose weight z into bf16 [C][R]; z==4 -> x cast (fp32 only) + bias ----
__global__ __launch_bounds__(256) void prep(const void* __restrict__ Wq,
                                            const void* __restrict__ Wk,
                                            const void* __restrict__ Wv,
                                            const void* __restrict__ Wo,
                                            const void* __restrict__ x,
                                            const void* __restrict__ bq,
                                            const void* __restrict__ bk,
                                            const void* __restrict__ bv,
                                            const void* __restrict__ bo,
                                            __bf16* __restrict__ Wt,
                                            __bf16* __restrict__ Wot,
                                            __bf16* __restrict__ x_bf,
                                            float* __restrict__ bias) {
  __shared__ float tile[32][33];
  const int isbf = detect_isbf((const unsigned short*)x);
  const int tid = threadIdx.x;
  const int z = blockIdx.z;

  if (z < 4) {
    const void* in = (z == 0) ? Wq : (z == 1) ? Wk : (z == 2) ? Wv : Wo;
    __bf16* out = (z < 3) ? (Wt + (size_t)z * 1024 * 1024) : Wot;
    const int tx = tid & 31, ty = tid >> 5;
    const int r0 = blockIdx.y * 32, c0 = blockIdx.x * 32;
#pragma unroll
    for (int i = 0; i < 4; i++) {
      int r = ty + i * 8;
      tile[r][tx] = ldf(in, (size_t)(r0 + r) * 1024 + c0 + tx, isbf);
    }
    __syncthreads();
#pragma unroll
    for (int i = 0; i < 4; i++) {
      int r = ty + i * 8;
      out[(size_t)(c0 + r) * 1024 + r0 + tx] = (__bf16)tile[tx][r];
    }
  } else {
    const int id = blockIdx.y * 32 + blockIdx.x;  // 0..1023
    if (!isbf) {
#pragma unroll
      for (int j = 0; j < 4; j++) {
        int idx = id * 1024 + j * 256 + tid;
        float4 f = ((const float4*)x)[idx];
        union { __bf16 h[4]; uint2 u; } pk;
        pk.h[0] = (__bf16)f.x; pk.h[1] = (__bf16)f.y;
        pk.h[2] = (__bf16)f.z; pk.h[3] = (__bf16)f.w;
        ((uint2*)x_bf)[idx] = pk.u;
      }
    }
    if (id < 16) {
      int i = id * 256 + tid;
      if (i < 1024)      bias[i] = ldf(bq, i, isbf);
      else if (i < 2048) bias[i] = ldf(bk, i - 1024, isbf);
      else if (i < 3072) bias[i] = ldf(bv, i - 2048, isbf);
      else               bias[i] = ldf(bo, i - 3072, isbf);
    }
  }
}

// ---------------- GEMM: C[M,NT-tiled] = A[M,K] @ Bt[N,K]^T + bias ----------------
// __launch_bounds__(256,3): cap VGPR ~170 -> 3 blocks/CU so barrier stalls interleave
// across blocks (m97 occupancy regime).
template <int DYN, int NT, int ALT>
__global__ __launch_bounds__(256, 3) void gemm_bt(const __bf16* __restrict__ A,
                                                  const __bf16* __restrict__ Aalt,
                                                  const __bf16* __restrict__ Bt,
                                                  const float* __restrict__ bias,
                                                  void* __restrict__ Cout,
                                                  const unsigned short* __restrict__ xdet,
                                                  int M, int N, int K) {
  constexpr int WN = NT / 2;
  constexpr int JB = WN / 16;
  constexpr int NR = NT / 32;
  __shared__ __align__(16) __bf16 As[128 * 64];
  __shared__ __align__(16) __bf16 Bs[NT * 64];
  const int tid = threadIdx.x;
  const int wid = tid >> 6, lane = tid & 63;
  const int m_blk = blockIdx.x * 128, n_blk = blockIdx.y * NT;
  const int wm = (wid & 1) * 64, wn = (wid >> 1) * WN;
  const int l8 = lane >> 3, l7 = lane & 7;
  const int cc = l7 ^ (l8 & 7);
  const int q4 = lane >> 4, l15 = lane & 15;

  int isbf = 1;
  if (DYN || ALT) isbf = detect_isbf(xdet);
  const __bf16* Ap = (ALT && isbf) ? Aalt : A;

  f32x4 acc[4][JB] = {};

  for (int kb = 0; kb < K; kb += 64) {
    __syncthreads();
#pragma unroll
    for (int i = 0; i < 4; i++) {
      int row = i * 32 + wid * 8 + l8;
      async_copy16(Ap + (size_t)(m_blk + row) * K + kb + cc * 8,
                   As + (i * 32 + wid * 8) * 64);
    }
#pragma unroll
    for (int i = 0; i < NR; i++) {
      int row = i * 32 + wid * 8 + l8;
      async_copy16(Bt + (size_t)(n_blk + row) * K + kb + cc * 8,
                   Bs + (i * 32 + wid * 8) * 64);
    }
    __syncthreads();
#pragma unroll
    for (int k0 = 0; k0 < 64; k0 += 32) {
      bf16x8 a[4], b[JB];
#pragma unroll
      for (int i = 0; i < 4; i++) {
        int ra = wm + i * 16 + l15;
        int ba = ra * 8 + (((k0 >> 3) + q4) ^ (ra & 7));
        a[i] = *(const bf16x8*)&As[ba * 8];
      }
#pragma unroll
      for (int j = 0; j < JB; j++) {
        int rb = wn + j * 16 + l15;
        int bb = rb * 8 + (((k0 >> 3) + q4) ^ (rb & 7));
        b[j] = *(const bf16x8*)&Bs[bb * 8];
      }
#pragma unroll
      for (int i = 0; i < 4; i++)
#pragma unroll
        for (int j = 0; j < JB; j++)
          acc[i][j] = __builtin_amdgcn_mfma_f32_16x16x32_bf16(a[i], b[j], acc[i][j], 0, 0, 0);
    }
  }

  float bcol[JB];
#pragma unroll
  for (int j = 0; j < JB; j++) bcol[j] = bias[n_blk + wn + j * 16 + l15];
#pragma unroll
  for (int i = 0; i < 4; i++)
#pragma unroll
    for (int j = 0; j < JB; j++) {
      int col = n_blk + wn + j * 16 + l15;
#pragma unroll
      for (int r = 0; r < 4; r++) {
        int row = m_blk + wm + i * 16 + q4 * 4 + r;
        float v = acc[i][j][r] + bcol[j];
        size_t idx = (size_t)row * N + col;
        if (DYN && !isbf) ((float*)Cout)[idx] = v;
        else              ((__bf16*)Cout)[idx] = (__bf16)v;
      }
    }
}

// ---------------- LN + RoPE + V-transpose (fused) ----------------
__global__ __launch_bounds__(256) void ln_rope_v(const __bf16* __restrict__ qkv,
                                                 const void* __restrict__ rcos,
                                                 const void* __restrict__ rsin,
                                                 const void* __restrict__ qw,
                                                 const void* __restrict__ qb,
                                                 const void* __restrict__ kw,
                                                 const void* __restrict__ kb_,
                                                 const unsigned short* __restrict__ xdet,
                                                 __bf16* __restrict__ Qp,
                                                 __bf16* __restrict__ Kp,
                                                 __bf16* __restrict__ Vt) {
  __shared__ __bf16 vt[64][68];
  const int isbf = detect_isbf(xdet);
  const int tid = threadIdx.x, w = tid >> 6, lane = tid & 63;
  const int bh = blockIdx.y, h = bh & 15, b = bh >> 4;
  const int n0 = blockIdx.x * 64;

  float gq = ldf(qw, lane, isbf), bq_ = ldf(qb, lane, isbf);
  float gk = ldf(kw, lane, isbf), bk_ = ldf(kb_, lane, isbf);

  for (int t = 0; t < 16; t++) {
    const int n = n0 + w * 16 + t;
    const size_t tok = (size_t)b * 2048 + n;
    const __bf16* base = qkv + tok * 3072 + h * 192;
    float qv = (float)base[lane], kv = (float)base[64 + lane], vv = (float)base[128 + lane];

    float sq = qv, sk = kv;
#pragma unroll
    for (int m = 1; m < 64; m <<= 1) { sq += __shfl_xor(sq, m, 64); sk += __shfl_xor(sk, m, 64); }
    float muq = sq * (1.0f / 64.0f), muk = sk * (1.0f / 64.0f);
    float tq = qv - muq, tk = kv - muk;
    float vq = tq * tq, vk = tk * tk;
#pragma unroll
    for (int m = 1; m < 64; m <<= 1) { vq += __shfl_xor(vq, m, 64); vk += __shfl_xor(vk, m, 64); }
    float rsq = rsqrtf(vq * (1.0f / 64.0f) + 1e-6f);
    float rsk = rsqrtf(vk * (1.0f / 64.0f) + 1e-6f);
    float qn = tq * rsq * gq + bq_;
    float kn = tk * rsk * gk + bk_;

    float c = ldf(rcos, tok * 64 + lane, isbf), s = ldf(rsin, tok * 64 + lane, isbf);
    float qpart = __shfl_xor(qn, 32, 64), kpart = __shfl_xor(kn, 32, 64);
    float qrh = (lane < 32) ? -qpart : qpart;
    float krh = (lane < 32) ? -kpart : kpart;

    const size_t oidx = ((size_t)bh * 2048 + n) * 64 + lane;
    Qp[oidx] = (__bf16)((qn * c + qrh * s) * 0.1803368801111204f);  // 0.125 * log2(e)
    Kp[oidx] = (__bf16)(kn * c + krh * s);
    vt[lane][w * 16 + t] = (__bf16)vv;
  }
  __syncthreads();
  const int row = tid >> 2, qt = tid & 3;
  size_t gbase = (size_t)bh * 64 * 2048 + (size_t)row * 2048 + n0 + qt * 16;
#pragma unroll
  for (int u = 0; u < 4; u++)
    *(uint2*)&Vt[gbase + u * 4] = *(const uint2*)&vt[row][qt * 16 + u * 4];
}

// ---------------- flash attention: K-split x2, KT=32, VALU-lean softmax ----------------
// VALU cuts this round: (1) l accumulated by ones-row MFMA on the idle matrix pipe
// (replaces 16 v_adds/iter + epilogue shfls; consistent with the quantized P used in
// PV); (2) P packed to bf16 by truncation via v_perm (1 instr / 2 elems, replaces
// cvt+or); (3) raw v_exp_f32 via builtin.
__global__ __launch_bounds__(256, 4) void attn(const __bf16* __restrict__ Qp,
                                               const __bf16* __restrict__ Kp,
                                               const __bf16* __restrict__ Vt,
                                               float* __restrict__ O0,
                                               float* __restrict__ O1,
                                               float* __restrict__ lpart) {
  __shared__ __align__(16) __bf16 sK[2][2048];   // [buf][(g=ks*2+c)*64+lane]*8
  __shared__ __align__(16) __bf16 sV[2][2048];   // [buf][(ds*64+lane)]*8
  __shared__ __align__(16) __bf16 sP[4][1024];   // per-wave, B-frag order (32q x 32k)

  const int tid = threadIdx.x, wid = tid >> 6, lane = tid & 63;
  const int q4 = lane >> 4, l15 = lane & 15;
  const int bh = blockIdx.y, split = blockIdx.z;
  const int q0w = blockIdx.x * 128 + wid * 32;
  const int kt0 = split * 1024;
  const __bf16* Qb = Qp + (size_t)bh * 2048 * 64;
  const __bf16* Kb = Kp + (size_t)bh * 2048 * 64;
  const __bf16* Vb = Vt + (size_t)bh * 64 * 2048;
  float* Op = split ? O1 : O0;
  __bf16* sPw = &sP[wid][0];
  const int pbase = (q4 >> 1) * 128 + l15 * 8 + (q4 & 1) * 4;

  // Q fragments (B-operand): B[q=l15][k=q4*8+j], 2 chains of 32 d
  bf16x8 qf[2][2];
#pragma unroll
  for (int qs = 0; qs < 2; qs++)
#pragma unroll
    for (int c = 0; c < 2; c++)
      qf[qs][c] = *(const bf16x8*)&Qb[(size_t)(q0w + qs * 16 + l15) * 64 + c * 32 + q4 * 8];

  // all-ones A-fragment: every row of the 16x32 A tile = 1.0 -> C[m][q] = sum_k P[k][q]
  bf16x8 ones8;
#pragma unroll
  for (int i = 0; i < 8; i++) ones8[i] = (__bf16)1.0f;

  f32x4 o[2][4] = {};
  f32x4 l_acc[2] = {};

#define STAGE(kt, bf)                                                                    \
  do {                                                                                   \
    async_copy16(Kb + (size_t)((kt) + (wid >> 1) * 16 + l15) * 64 + (wid & 1) * 32 + q4 * 8, \
                 &sK[bf][wid * 512]);                                                    \
    async_copy16(Vb + (size_t)(wid * 16 + l15) * 2048 + (kt) + q4 * 8,                   \
                 &sV[bf][wid * 512]);                                                    \
  } while (0)

  STAGE(kt0, 0);

  for (int it = 0; it < 32; ++it) {
    const int buf = it & 1;
    __syncthreads();  // readers of buf^1 done + loads into buf landed
    if (it < 31) STAGE(kt0 + (it + 1) * 32, buf ^ 1);

    // ---- QK^T (S^T): A = K rows (2 ks-subs), B = Q (2 q-subs), 2 d-chains ----
    bf16x8 ak[2][2];
#pragma unroll
    for (int ks = 0; ks < 2; ks++)
#pragma unroll
      for (int c = 0; c < 2; c++)
        ak[ks][c] = *(const bf16x8*)&sK[buf][((ks * 2 + c) * 64 + lane) * 8];
    f32x4 sc[2][2];
#pragma unroll
    for (int qs = 0; qs < 2; qs++)
#pragma unroll
      for (int ks = 0; ks < 2; ks++) {
        f32x4 z = {0.f, 0.f, 0.f, 0.f};
        z = __builtin_amdgcn_mfma_f32_16x16x32_bf16(ak[ks][0], qf[qs][0], z, 0, 0, 0);
        z = __builtin_amdgcn_mfma_f32_16x16x32_bf16(ak[ks][1], qf[qs][1], z, 0, 0, 0);
        sc[qs][ks] = z;
      }

    // ---- no-max softmax: p = exp2(s); truncate-pack to bf16 via v_perm ----
#pragma unroll
    for (int qs = 0; qs < 2; qs++)
#pragma unroll
      for (int ks = 0; ks < 2; ks++) {
        uint2 pk;
        {
          float p0 = __builtin_amdgcn_exp2f(sc[qs][ks][0]);
          float p1 = __builtin_amdgcn_exp2f(sc[qs][ks][1]);
          pk.x = __builtin_amdgcn_perm(__builtin_bit_cast(unsigned int, p1),
                                       __builtin_bit_cast(unsigned int, p0), 0x07060302u);
          float p2 = __builtin_amdgcn_exp2f(sc[qs][ks][2]);
          float p3 = __builtin_amdgcn_exp2f(sc[qs][ks][3]);
          pk.y = __builtin_amdgcn_perm(__builtin_bit_cast(unsigned int, p3),
                                       __builtin_bit_cast(unsigned int, p2), 0x07060302u);
        }
        *(uint2*)&sPw[qs * 512 + ks * 256 + pbase] = pk;
      }
    asm volatile("s_waitcnt lgkmcnt(0)" ::: "memory");  // P writes -> reads (same wave)

    // ---- PV (O^T += V^T.P) + l += ones.P on the matrix pipe ----
    bf16x8 pb[2];
#pragma unroll
    for (int qs = 0; qs < 2; qs++)
      pb[qs] = *(const bf16x8*)&sPw[(qs * 64 + lane) * 8];
#pragma unroll
    for (int qs = 0; qs < 2; qs++)
      l_acc[qs] = __builtin_amdgcn_mfma_f32_16x16x32_bf16(ones8, pb[qs], l_acc[qs], 0, 0, 0);
#pragma unroll
    for (int ds = 0; ds < 4; ds++) {
      bf16x8 av = *(const bf16x8*)&sV[buf][(ds * 64 + lane) * 8];
#pragma unroll
      for (int qs = 0; qs < 2; qs++)
        o[qs][ds] = __builtin_amdgcn_mfma_f32_16x16x32_bf16(av, pb[qs], o[qs][ds], 0, 0, 0);
    }
  }
#undef STAGE

  // ---- epilogue: partial O (fp32, [bh][q][d]) and partial l (no shfls needed) ----
#pragma unroll
  for (int qs = 0; qs < 2; qs++) {
    const int q = q0w + qs * 16 + l15;
    if (q4 == 0) lpart[(size_t)(split * 32 + bh) * 2048 + q] = l_acc[qs][0];
    size_t base = ((size_t)bh * 2048 + q) * 64;
#pragma unroll
    for (int ds = 0; ds < 4; ds++)
      *(f32x4*)&Op[base + ds * 16 + q4 * 4] = o[qs][ds];
  }
}

// ---------------- combine: Obuf = (O0+O1) / (l0+l1), bf16 [b][q][h*64+d] ----------------
__global__ __launch_bounds__(256) void combine(const float* __restrict__ O0,
                                               const float* __restrict__ O1,
                                               const float* __restrict__ lpart,
                                               __bf16* __restrict__ Obuf) {
  const int idx = blockIdx.x * 256 + threadIdx.x;  // 1,048,576 threads x 4 d
  const int d4 = idx & 15, q = (idx >> 4) & 2047, bh = idx >> 15;
  const int b = bh >> 4, h = bh & 15;
  const size_t po = ((size_t)bh * 2048 + q) * 64 + d4 * 4;
  f32x4 a = *(const f32x4*)&O0[po];
  f32x4 c = *(const f32x4*)&O1[po];
  float l = lpart[(size_t)bh * 2048 + q] + lpart[(size_t)(32 + bh) * 2048 + q];
  float rl = 1.0f / l;
  union { __bf16 h4[4]; uint2 u; } pk;
#pragma unroll
  for (int r = 0; r < 4; r++) pk.h4[r] = (__bf16)((a[r] + c[r]) * rl);
  *(uint2*)&Obuf[((size_t)(b * 2048 + q)) * 1024 + h * 64 + d4 * 4] = pk.u;
}

extern "C" void kernel_launch(void* const* d_in, const int* in_sizes, int n_in,
                              void* d_out, int out_size, void* d_ws, size_t ws_size,
                              hipStream_t stream) {
  const void* x   = d_in[0];
  const void* rc  = d_in[1];
  const void* rs  = d_in[2];
  const void* Wq  = d_in[3];
  const void* bq  = d_in[4];
  const void* Wk  = d_in[5];
  const void* bk  = d_in[6];
  const void* Wv  = d_in[7];
  const void* bv  = d_in[8];
  const void* qnw = d_in[9];
  const void* qnb = d_in[10];
  const void* knw = d_in[11];
  const void* knb = d_in[12];
  const void* Wo  = d_in[13];
  const void* bo  = d_in[14];
  const unsigned short* xdet = (const unsigned short*)x;

  // temporal aliasing plan:
  //  [0, 25165824)        qkv bf16 (gemm0 -> ln_rope_v), then O0/O1 fp32 partials
  //  [25165824, 33554432) x_bf (prep -> gemm0, fp32 path only)
  //  [33554432, 41943040) Qp, then Obuf (combine -> gemm1)
  char* ws = (char*)d_ws;
  __bf16* qkv  = (__bf16*)ws;
  float*  O0   = (float*)ws;
  float*  O1   = (float*)(ws + 16777216);
  __bf16* x_bf = (__bf16*)(ws + 25165824);
  __bf16* Qp   = (__bf16*)(ws + 33554432);
  __bf16* Obuf = (__bf16*)(ws + 33554432);
  __bf16* Kp   = (__bf16*)(ws + 41943040);
  __bf16* Vt   = (__bf16*)(ws + 50331648);
  __bf16* Wt   = (__bf16*)(ws + 58720256);   // [3072][1024] 6 MB
  __bf16* Wot  = (__bf16*)(ws + 65011712);   // [1024][1024] 2 MB
  float*  bias = (float*)(ws + 67108864);    // [4096]
  float*  lprt = (float*)(ws + 67125248);    // [2][32][2048] 512 KB

  prep<<<dim3(32, 32, 5), 256, 0, stream>>>(Wq, Wk, Wv, Wo, x, bq, bk, bv, bo,
                                            Wt, Wot, x_bf, bias);
  gemm_bt<0, 128, 1><<<dim3(32, 24), 256, 0, stream>>>(x_bf, (const __bf16*)x, Wt, bias,
                                                       qkv, xdet, 4096, 3072, 1024);
  ln_rope_v<<<dim3(32, 32), 256, 0, stream>>>(qkv, rc, rs, qnw, qnb, knw, knb, xdet,
                                              Qp, Kp, Vt);
  attn<<<dim3(16, 32, 2), 256, 0, stream>>>(Qp, Kp, Vt, O0, O1, lprt);
  combine<<<4096, 256, 0, stream>>>(O0, O1, lprt, Obuf);
  gemm_bt<1, 64, 0><<<dim3(32, 16), 256, 0, stream>>>(Obuf, nullptr, Wot, bias + 3072,
                                                      d_out, xdet, 4096, 1024, 1024);
}